// Round 1
// baseline (117.969 us; speedup 1.0000x reference)
//
#include <hip/hip_runtime.h>
#include <math.h>

// Problem constants (match reference)
#define BATCH 16384
#define NN    1024
#define NI    128
#define NO    64
#define REFR  0.9f

typedef float  f32x4  __attribute__((ext_vector_type(4)));
typedef __bf16 bf16x8 __attribute__((ext_vector_type(8)));

// ---------------------------------------------------------------------------
// Kernel 1: pack W[:, 960:1024] into bf16 B-fragments for mfma_f32_16x16x32_bf16,
// WITH the refractory scale folded in: rows k in [128,960) are pre-multiplied
// by 0.9 (scale is per-k, so scaling W is identical to scaling states).
// Frag layout (consumed by fused kernel): element j of frag[(kc*4+tn)*64 + l]
//   = W[kc*32 + (l>>4)*8 + j][960 + tn*16 + (l&15)]   [m89 B-layout]
// ---------------------------------------------------------------------------
__global__ __launch_bounds__(256) void pack_w_kernel(const float* __restrict__ W,
                                                     __bf16* __restrict__ wsB) {
    int idx = blockIdx.x * 256 + threadIdx.x;   // 0 .. 65535
    int k = idx >> 6;        // 0..1023
    int n = idx & 63;        // 0..63
    float v = W[(size_t)k * NN + (NN - NO) + n];
    int kc = k >> 5;
    if (kc >= 4 && kc < 30) v *= REFR;          // fold refractory factor
    int kk = k & 31;
    int r3 = kk >> 3;        // l>>4
    int j  = kk & 7;
    int tn = n >> 4;
    int l  = r3 * 16 + (n & 15);
    wsB[(size_t)(((kc * 4 + tn) * 64 + l) * 8 + j)] = (__bf16)v;
}

__device__ inline float activate(float x, int id) {
    if (id == 0) return fmaxf(x, 0.0f);
    if (id == 1) return tanhf(x);
    if (id == 2) return 1.0f / (1.0f + __expf(-x));
    return x;
}

// ---------------------------------------------------------------------------
// Kernel 2: fused input-assign + GEMM (M=16384, N=64, K=1024) + bias + act.
// v2 changes vs previous round:
//  * 32 rows per block (two 16-row M-tiles) -> each B-fragment load feeds TWO
//    MFMAs; wsB L2 traffic halves (128 MB -> 64 MB across the launch).
//  * Non-temporal A loads (prev/inp are streamed exactly once) so the 64 MB
//    stream stops evicting the hot 128 KB wsB from the per-XCD L2s.
//  * Deep explicit A staging: 16 global_load_dwordx4 issued before first use,
//    4-chunk software pipeline after -> ~16-20 KB per wave in flight
//    (Little's law needs ~9 KB/CU at ~900cy miss latency, 8 waves/CU resident).
//  * __launch_bounds__(256,2): grid is 512 blocks = 2 blocks/CU, so cap VGPR
//    at 256 instead of 128 and let the scheduler keep loads outstanding.
// Numerics identical to v1: same per-wave K partition, same fp32 accum order.
// ---------------------------------------------------------------------------
__global__ __launch_bounds__(256, 2) void fused_rnn_kernel(
    const float* __restrict__ prev,
    const float* __restrict__ inp,
    const __bf16* __restrict__ wsB,
    const float* __restrict__ bias,
    const int*  __restrict__ act,
    float* __restrict__ out)
{
    const int lane = threadIdx.x & 63;
    const int wv   = threadIdx.x >> 6;   // K-split index, 0..3
    const int m    = lane & 15;          // A-row within tile
    const int q    = lane >> 4;          // quad
    const int row0 = blockIdx.x * 32;    // two 16-row tiles per block

    const float* prow0 = prev + (size_t)(row0 + m) * NN;
    const float* prow1 = prev + (size_t)(row0 + 16 + m) * NN;
    const float* irow0 = inp  + (size_t)(row0 + m) * NI;
    const float* irow1 = inp  + (size_t)(row0 + 16 + m) * NI;
    const bf16x8* Bf   = (const bf16x8*)wsB;
    const int qo = q * 8;

    f32x4 acc0[4], acc1[4];
#pragma unroll
    for (int t = 0; t < 4; ++t) {
        acc0[t] = (f32x4){0.f, 0.f, 0.f, 0.f};
        acc1[t] = acc0[t];
    }

    // A staging registers. All indices become compile-time constants after
    // full unroll -> pure registers (rule: no runtime-indexed arrays).
    f32x4 A0a[8], A0b[8], A1a[8], A1b[8];

#define LOADC(i) {                                                           \
        const int kc_ = wv * 8 + (i);                                        \
        const float* s0_ = (kc_ < 4) ? irow0 : prow0;                        \
        const float* s1_ = (kc_ < 4) ? irow1 : prow1;                        \
        const f32x4* p0_ = (const f32x4*)(s0_ + kc_ * 32 + qo);              \
        const f32x4* p1_ = (const f32x4*)(s1_ + kc_ * 32 + qo);              \
        A0a[i] = __builtin_nontemporal_load(p0_);                            \
        A0b[i] = __builtin_nontemporal_load(p0_ + 1);                        \
        A1a[i] = __builtin_nontemporal_load(p1_);                            \
        A1b[i] = __builtin_nontemporal_load(p1_ + 1);                        \
    }

    // Prologue: 4 chunks (16 loads) in flight before first MFMA.
#pragma unroll
    for (int i = 0; i < 4; ++i) LOADC(i)

#pragma unroll
    for (int i = 0; i < 8; ++i) {
        if (i < 4) LOADC(i + 4)      // keep pipeline 4 chunks deep
        const int kc = wv * 8 + i;

        bf16x8 a0, a1;
#pragma unroll
        for (int e = 0; e < 4; ++e) {
            a0[e]     = (__bf16)A0a[i][e];
            a0[e + 4] = (__bf16)A0b[i][e];
            a1[e]     = (__bf16)A1a[i][e];
            a1[e + 4] = (__bf16)A1b[i][e];
        }

        const bf16x8* bp = Bf + (size_t)kc * 256 + lane;
        bf16x8 b0 = bp[0];
        bf16x8 b1 = bp[64];
        bf16x8 b2 = bp[128];
        bf16x8 b3 = bp[192];

        // Each B fragment feeds both M-tiles.
        acc0[0] = __builtin_amdgcn_mfma_f32_16x16x32_bf16(a0, b0, acc0[0], 0, 0, 0);
        acc1[0] = __builtin_amdgcn_mfma_f32_16x16x32_bf16(a1, b0, acc1[0], 0, 0, 0);
        acc0[1] = __builtin_amdgcn_mfma_f32_16x16x32_bf16(a0, b1, acc0[1], 0, 0, 0);
        acc1[1] = __builtin_amdgcn_mfma_f32_16x16x32_bf16(a1, b1, acc1[1], 0, 0, 0);
        acc0[2] = __builtin_amdgcn_mfma_f32_16x16x32_bf16(a0, b2, acc0[2], 0, 0, 0);
        acc1[2] = __builtin_amdgcn_mfma_f32_16x16x32_bf16(a1, b2, acc1[2], 0, 0, 0);
        acc0[3] = __builtin_amdgcn_mfma_f32_16x16x32_bf16(a0, b3, acc0[3], 0, 0, 0);
        acc1[3] = __builtin_amdgcn_mfma_f32_16x16x32_bf16(a1, b3, acc1[3], 0, 0, 0);
    }
#undef LOADC

    // ---- Cross-wave K-reduction via LDS ----
    // D layout: col = t*16 + m, row = q*4 + r  [measured m89]
    __shared__ __align__(16) float red[4][2][16][68];   // [wave][tile][row][col] (+4 pad)
#pragma unroll
    for (int t = 0; t < 4; ++t) {
#pragma unroll
        for (int r = 0; r < 4; ++r) {
            red[wv][0][q * 4 + r][t * 16 + m] = acc0[t][r];
            red[wv][1][q * 4 + r][t * 16 + m] = acc1[t][r];
        }
    }
    __syncthreads();

    // Each thread produces one float4 of output for BOTH tiles:
    // row = tid>>4, cols [(tid&15)*4, +4).
    const int orow = threadIdx.x >> 4;       // 0..15
    const int oc   = (threadIdx.x & 15) * 4; // 0..60

    f32x4 s0 = *(const f32x4*)&red[0][0][orow][oc];
    f32x4 s1 = *(const f32x4*)&red[0][1][orow][oc];
#pragma unroll
    for (int w = 1; w < 4; ++w) {
        s0 += *(const f32x4*)&red[w][0][orow][oc];
        s1 += *(const f32x4*)&red[w][1][orow][oc];
    }

    const float* bo = bias + (NN - NO);
    const int*   ao = act  + (NN - NO);
    f32x4 o0, o1;
#pragma unroll
    for (int c = 0; c < 4; ++c) {
        const float b  = bo[oc + c];
        const int   id = ao[oc + c];
        o0[c] = activate(s0[c] + b, id);
        o1[c] = activate(s1[c] + b, id);
    }
    *(f32x4*)(out + (size_t)(row0 + orow) * NO + oc)      = o0;
    *(f32x4*)(out + (size_t)(row0 + 16 + orow) * NO + oc) = o1;
}

extern "C" void kernel_launch(void* const* d_in, const int* in_sizes, int n_in,
                              void* d_out, int out_size, void* d_ws, size_t ws_size,
                              hipStream_t stream) {
    const float* prev = (const float*)d_in[0];   // [B, N] fp32
    const float* inp  = (const float*)d_in[1];   // [B, I] fp32
    const float* W    = (const float*)d_in[2];   // [N, N] fp32
    const float* bias = (const float*)d_in[3];   // [N]    fp32
    const int*   act  = (const int*)  d_in[4];   // [N]    int32
    float* out = (float*)d_out;                  // [B, O] fp32
    __bf16* wsB = (__bf16*)d_ws;                 // 65536 bf16 = 128 KB

    // Pack (and pre-scale) W slice into MFMA B-fragment order. ws is re-poisoned
    // by the harness each call, so this runs every launch (~0.5 MB traffic).
    pack_w_kernel<<<256, 256, 0, stream>>>(W, wsB);

    // Main fused kernel: one block per 32-row tile-pair, K-split x4 inside.
    fused_rnn_kernel<<<BATCH / 32, 256, 0, stream>>>(prev, inp, wsB, bias, act, out);
}

// Round 2
// 117.353 us; speedup vs baseline: 1.0053x; 1.0053x over previous
//
#include <hip/hip_runtime.h>
#include <math.h>

// Problem constants (match reference)
#define BATCH 16384
#define NN    1024
#define NI    128
#define NO    64
#define REFR  0.9f

typedef float  f32x4  __attribute__((ext_vector_type(4)));
typedef __bf16 bf16x8 __attribute__((ext_vector_type(8)));

__device__ inline float activate(float x, int id) {
    if (id == 0) return fmaxf(x, 0.0f);
    if (id == 1) return tanhf(x);
    if (id == 2) return 1.0f / (1.0f + __expf(-x));
    return x;
}

// ---------------------------------------------------------------------------
// Single fused kernel: W-slice pack (refractory folded) -> LDS, then
// input-assign + GEMM (M=16384, N=64, K=1024) + bias + heterogeneous act.
//
// v3 structure (vs v2's two-kernel pipeline):
//  * ONE launch, workspace-free: removes the pack kernel, its launch gap, and
//    the round-trip through the harness-poisoned ws buffer.
//  * 256 blocks x 512 threads = 1 block/CU, 8 waves resident.
//    Block owns 64 rows. Wave wv: ksplit = wv&3 (K-chunks [8*ks, 8*ks+8)),
//    mhalf = wv>>2 (rows [32*mh, 32*mh+32) as two 16-row M-tiles).
//    Per-wave work identical to v2.
//  * W[:,960:1024] staged per-block from global (256 KB, L2-resident after
//    first touch) into 128 KB of LDS in MFMA B-fragment order [m89 layout]:
//    element j of frag[(kc*4+tn)*64 + l] = W[kc*32+(l>>4)*8+j][960+tn*16+(l&15)]
//    (rows 128..959 pre-scaled by 0.9 = refractory fold; per-k scale on W is
//    identical to scaling states).
//  * A-load prologue (non-temporal, 4 chunks deep) issued BEFORE the W staging
//    loop so HBM latency hides under the L2-bound pack phase.
//  * After the K-loop a barrier lets us REUSE the same LDS for the cross-wave
//    K-reduction (70 KB < 128 KB), keeping total LDS at 128 KB (<160 KB/CU).
// Numerics: same MFMA order, same fp32 partial-sum order as v2.
// ---------------------------------------------------------------------------
__global__ __launch_bounds__(512, 1) void fused_rnn_kernel(
    const float* __restrict__ prev,
    const float* __restrict__ inp,
    const float* __restrict__ W,
    const float* __restrict__ bias,
    const int*  __restrict__ act,
    float* __restrict__ out)
{
    __shared__ __align__(16) char smem[131072];   // 128 KB, dual-purpose
    __bf16* wlds = (__bf16*)smem;                 // phase 1: B fragments
    float*  redf = (float*)smem;                  // phase 2: reduction

    const int tid  = threadIdx.x;        // 0..511
    const int lane = tid & 63;
    const int wv   = tid >> 6;           // 0..7
    const int ks   = wv & 3;             // K-split index
    const int mh   = wv >> 2;            // M-half (0: rows 0..31, 1: rows 32..63)
    const int m    = lane & 15;          // A-row within 16-row tile
    const int q    = lane >> 4;          // quad
    const int qo   = q * 8;
    const int row0 = blockIdx.x * 64;

    const float* prow0 = prev + (size_t)(row0 + mh * 32 + m) * NN;
    const float* prow1 = prev + (size_t)(row0 + mh * 32 + 16 + m) * NN;
    const float* irow0 = inp  + (size_t)(row0 + mh * 32 + m) * NI;
    const float* irow1 = inp  + (size_t)(row0 + mh * 32 + 16 + m) * NI;

    // ---- A prologue: 4 K-chunks (16 nontemporal dwordx4 loads) in flight ----
    f32x4 A0a[8], A0b[8], A1a[8], A1b[8];

#define LOADC(i) {                                                           \
        const int kc_ = ks * 8 + (i);                                        \
        const float* s0_ = (kc_ < 4) ? irow0 : prow0;                        \
        const float* s1_ = (kc_ < 4) ? irow1 : prow1;                        \
        const f32x4* p0_ = (const f32x4*)(s0_ + kc_ * 32 + qo);              \
        const f32x4* p1_ = (const f32x4*)(s1_ + kc_ * 32 + qo);              \
        A0a[i] = __builtin_nontemporal_load(p0_);                            \
        A0b[i] = __builtin_nontemporal_load(p0_ + 1);                        \
        A1a[i] = __builtin_nontemporal_load(p1_);                            \
        A1b[i] = __builtin_nontemporal_load(p1_ + 1);                        \
    }

#pragma unroll
    for (int i = 0; i < 4; ++i) LOADC(i)

    // ---- W staging: 8192 fragments, 16 per thread, wave-contiguous ids ----
    // Fragment f: kc = f>>8, tn = (f>>6)&3, l = f&63. Each fragment = 8 scalar
    // W loads (8 consecutive rows, one col) -> one 16 B LDS write.
    for (int it = 0; it < 16; ++it) {
        const int f  = it * 512 + tid;
        const int kc = f >> 8;
        const int tn = (f >> 6) & 3;
        const int l  = f & 63;
        const int col  = (NN - NO) + tn * 16 + (l & 15);
        const int rowb = kc * 32 + ((l >> 4) << 3);
        const float sc = (kc >= 4 && kc < 30) ? REFR : 1.0f;
        bf16x8 frag;
#pragma unroll
        for (int j = 0; j < 8; ++j) {
            float v = W[(size_t)(rowb + j) * NN + col] * sc;
            frag[j] = (__bf16)v;
        }
        *(bf16x8*)(wlds + (size_t)f * 8) = frag;
    }
    __syncthreads();

    // ---- K-loop: 8 chunks, 2 M-tiles, B fragments from LDS ----
    f32x4 acc0[4], acc1[4];
#pragma unroll
    for (int t = 0; t < 4; ++t) {
        acc0[t] = (f32x4){0.f, 0.f, 0.f, 0.f};
        acc1[t] = acc0[t];
    }

#pragma unroll
    for (int i = 0; i < 8; ++i) {
        if (i < 4) LOADC(i + 4)      // keep A pipeline 4 chunks deep
        const int kc = ks * 8 + i;

        bf16x8 a0, a1;
#pragma unroll
        for (int e = 0; e < 4; ++e) {
            a0[e]     = (__bf16)A0a[i][e];
            a0[e + 4] = (__bf16)A0b[i][e];
            a1[e]     = (__bf16)A1a[i][e];
            a1[e + 4] = (__bf16)A1b[i][e];
        }

        const bf16x8* bp = (const bf16x8*)wlds + (size_t)kc * 256 + lane;
        bf16x8 b0 = bp[0];
        bf16x8 b1 = bp[64];
        bf16x8 b2 = bp[128];
        bf16x8 b3 = bp[192];

        acc0[0] = __builtin_amdgcn_mfma_f32_16x16x32_bf16(a0, b0, acc0[0], 0, 0, 0);
        acc1[0] = __builtin_amdgcn_mfma_f32_16x16x32_bf16(a1, b0, acc1[0], 0, 0, 0);
        acc0[1] = __builtin_amdgcn_mfma_f32_16x16x32_bf16(a0, b1, acc0[1], 0, 0, 0);
        acc1[1] = __builtin_amdgcn_mfma_f32_16x16x32_bf16(a1, b1, acc1[1], 0, 0, 0);
        acc0[2] = __builtin_amdgcn_mfma_f32_16x16x32_bf16(a0, b2, acc0[2], 0, 0, 0);
        acc1[2] = __builtin_amdgcn_mfma_f32_16x16x32_bf16(a1, b2, acc1[2], 0, 0, 0);
        acc0[3] = __builtin_amdgcn_mfma_f32_16x16x32_bf16(a0, b3, acc0[3], 0, 0, 0);
        acc1[3] = __builtin_amdgcn_mfma_f32_16x16x32_bf16(a1, b3, acc1[3], 0, 0, 0);
    }
#undef LOADC

    // ---- Cross-wave K-reduction: reuse smem (all wfrag reads done) ----
    __syncthreads();   // ensure every wave finished its LDS B-reads

    // red layout: [mh][ks][tile][row16][68] ; offset in floats:
    //   ((((mh*4+ks)*2+tile)*16+row)*68 + col)
    // D layout: col = t*16 + m, row = q*4 + r  [measured m89]
#pragma unroll
    for (int t = 0; t < 4; ++t) {
#pragma unroll
        for (int r = 0; r < 4; ++r) {
            redf[((((mh * 4 + ks) * 2 + 0) * 16 + (q * 4 + r)) * 68) + t * 16 + m] = acc0[t][r];
            redf[((((mh * 4 + ks) * 2 + 1) * 16 + (q * 4 + r)) * 68) + t * 16 + m] = acc1[t][r];
        }
    }
    __syncthreads();

    // ---- Epilogue: 1024 output float4s, 2 per thread ----
    const float* bo = bias + (NN - NO);
    const int*   ao = act  + (NN - NO);
#pragma unroll
    for (int pass = 0; pass < 2; ++pass) {
        const int T  = pass * 512 + tid;
        const int r  = T >> 4;           // 0..63 block-local row
        const int oc = (T & 15) * 4;     // 0..60
        const int rmh = r >> 5;
        const int rtl = (r >> 4) & 1;
        const int rm  = r & 15;

        f32x4 s = *(const f32x4*)&redf[((((rmh * 4 + 0) * 2 + rtl) * 16 + rm) * 68) + oc];
#pragma unroll
        for (int k = 1; k < 4; ++k) {
            s += *(const f32x4*)&redf[((((rmh * 4 + k) * 2 + rtl) * 16 + rm) * 68) + oc];
        }

        f32x4 o;
#pragma unroll
        for (int c = 0; c < 4; ++c) {
            o[c] = activate(s[c] + bo[oc + c], ao[oc + c]);
        }
        *(f32x4*)(out + (size_t)(row0 + r) * NO + oc) = o;
    }
}

extern "C" void kernel_launch(void* const* d_in, const int* in_sizes, int n_in,
                              void* d_out, int out_size, void* d_ws, size_t ws_size,
                              hipStream_t stream) {
    const float* prev = (const float*)d_in[0];   // [B, N] fp32
    const float* inp  = (const float*)d_in[1];   // [B, I] fp32
    const float* W    = (const float*)d_in[2];   // [N, N] fp32
    const float* bias = (const float*)d_in[3];   // [N]    fp32
    const int*   act  = (const int*)  d_in[4];   // [N]    int32
    float* out = (float*)d_out;                  // [B, O] fp32
    (void)d_ws; (void)ws_size;                   // workspace-free

    // Single fused launch: 1 block per 64-row tile, 1 block/CU (256 blocks).
    fused_rnn_kernel<<<BATCH / 64, 512, 0, stream>>>(prev, inp, W, bias, act, out);
}